// Round 1
// baseline (6430.602 us; speedup 1.0000x reference)
//
#include <hip/hip_runtime.h>
#include <cstdint>
#include <cstddef>

// Problem constants: B=64, T=512, I=128, H=256, 4H=1024, C=3
typedef _Float16 half2_t __attribute__((ext_vector_type(2)));

static __device__ __forceinline__ float fdot2(half2_t a, half2_t b, float c) {
    return __builtin_amdgcn_fdot2(a, b, c, false);  // v_dot2_f32_f16, fp32 accum
}
static __device__ __forceinline__ half2_t h2(unsigned int u) {
    return __builtin_bit_cast(half2_t, u);
}
static __device__ __forceinline__ float sigm(float x) {
    return 1.f / (1.f + __expf(-x));
}
static __device__ __forceinline__ float tanh_fast(float x) {
    // robust: no inf-inf; __expf(big)=inf -> 2/inf = 0
    float ax = fabsf(x);
    float e = __expf(2.f * ax);
    float r = 1.f - 2.f / (e + 1.f);
    return copysignf(r, x);
}

// ---------------------------------------------------------------------------
// prep: W_hh (1024x256 fp32) -> f16 packed k8-major: Wp[k8][row] = 8 halves
//       W[row][8*k8 .. 8*k8+7]; also bias = b_ih + b_hh
// ---------------------------------------------------------------------------
__global__ __launch_bounds__(256) void prep_whh(const float* __restrict__ Whh,
                                                const float* __restrict__ bih,
                                                const float* __restrict__ bhh,
                                                uint4* __restrict__ Wp,
                                                float* __restrict__ bias) {
    int n = blockIdx.x * 256 + threadIdx.x;  // 0..32767
    if (n < 1024) bias[n] = bih[n] + bhh[n];
    int row = n & 1023;
    int k8 = n >> 10;  // 0..31
    union { uint4 u; _Float16 h[8]; } cv;
#pragma unroll
    for (int j = 0; j < 8; ++j) cv.h[j] = (_Float16)Whh[row * 256 + k8 * 8 + j];
    Wp[k8 * 1024 + row] = cv.u;
}

// ---------------------------------------------------------------------------
// gemm_bias: C[M][1024] = A[M][K] * W[1024][K]^T + bias   (fp32, 64x64 tiles)
// grid = (M/64, 16), block = 256, each thread 4x4 micro-tile
// ---------------------------------------------------------------------------
__global__ __launch_bounds__(256) void gemm_bias(const float* __restrict__ A,
                                                 const float* __restrict__ W,
                                                 const float* __restrict__ bias,
                                                 float* __restrict__ Cmat,
                                                 int K) {
    __shared__ float As[64][65];  // row-major, pad 1 to break bank conflicts
    __shared__ float Ws[64][65];
    const int tid = threadIdx.x;
    const int tx = tid & 15, ty = tid >> 4;
    const int m0 = blockIdx.x * 64, n0 = blockIdx.y * 64;
    const int lm = tid >> 4;        // 0..15 (row group for staging)
    const int lk = (tid & 15) * 4;  // k offset for staging (float4)

    float acc[4][4] = {};

    for (int k0 = 0; k0 < K; k0 += 64) {
#pragma unroll
        for (int r = 0; r < 4; ++r) {
            int m = lm + r * 16;
            const float4 va = *(const float4*)(A + (size_t)(m0 + m) * K + k0 + lk);
            As[m][lk + 0] = va.x; As[m][lk + 1] = va.y;
            As[m][lk + 2] = va.z; As[m][lk + 3] = va.w;
            const float4 vw = *(const float4*)(W + (size_t)(n0 + m) * K + k0 + lk);
            Ws[m][lk + 0] = vw.x; Ws[m][lk + 1] = vw.y;
            Ws[m][lk + 2] = vw.z; Ws[m][lk + 3] = vw.w;
        }
        __syncthreads();
#pragma unroll 8
        for (int k = 0; k < 64; ++k) {
            float a[4], w[4];
#pragma unroll
            for (int i = 0; i < 4; ++i) a[i] = As[ty * 4 + i][k];
#pragma unroll
            for (int i = 0; i < 4; ++i) w[i] = Ws[tx * 4 + i][k];
#pragma unroll
            for (int i = 0; i < 4; ++i)
#pragma unroll
                for (int jj = 0; jj < 4; ++jj) acc[i][jj] += a[i] * w[jj];
        }
        __syncthreads();
    }

#pragma unroll
    for (int i = 0; i < 4; ++i) {
        const size_t mrow = (size_t)(m0 + ty * 4 + i);
#pragma unroll
        for (int jj = 0; jj < 4; ++jj) {
            int ncol = n0 + tx * 4 + jj;
            Cmat[mrow * 1024 + ncol] = acc[i][jj] + bias[ncol];
        }
    }
}

// ---------------------------------------------------------------------------
// lstm_scan: one WG per batch element; thread j owns hidden unit j.
// gx: [B][T][1024] precomputed x-gates (+bias); Wp: packed f16 W_hh;
// h_out: [B][T][256] fp32
// ---------------------------------------------------------------------------
__global__ __launch_bounds__(256) void lstm_scan(const float* __restrict__ gx,
                                                 const uint4* __restrict__ Wp,
                                                 float* __restrict__ h_out) {
    const int b = blockIdx.x;
    const int j = threadIdx.x;  // hidden unit 0..255
    __shared__ _Float16 hsh[256] __attribute__((aligned(16)));
    hsh[j] = (_Float16)0.f;
    float c = 0.f;
    const float* gxb = gx + (size_t)b * 512 * 1024;
    float* hob = h_out + (size_t)b * 512 * 256;
    __syncthreads();

    for (int t = 0; t < 512; ++t) {
        const float* g4 = gxb + t * 1024;
        // issue x-gate loads early; they are consumed after the k-loop
        float gi = g4[j], gf = g4[256 + j], gg = g4[512 + j], go = g4[768 + j];
        float a0 = 0.f, a1 = 0.f, a2 = 0.f, a3 = 0.f;
#pragma unroll 4
        for (int k8 = 0; k8 < 32; ++k8) {
            const uint4 hv = *(const uint4*)(hsh + k8 * 8);  // broadcast read
            const uint4 w0 = Wp[k8 * 1024 + j];        // coalesced 16B/lane
            const uint4 w1 = Wp[k8 * 1024 + 256 + j];
            const uint4 w2 = Wp[k8 * 1024 + 512 + j];
            const uint4 w3 = Wp[k8 * 1024 + 768 + j];
            const half2_t hh0 = h2(hv.x), hh1 = h2(hv.y), hh2 = h2(hv.z), hh3 = h2(hv.w);
            a0 = fdot2(h2(w0.x), hh0, a0); a0 = fdot2(h2(w0.y), hh1, a0);
            a0 = fdot2(h2(w0.z), hh2, a0); a0 = fdot2(h2(w0.w), hh3, a0);
            a1 = fdot2(h2(w1.x), hh0, a1); a1 = fdot2(h2(w1.y), hh1, a1);
            a1 = fdot2(h2(w1.z), hh2, a1); a1 = fdot2(h2(w1.w), hh3, a1);
            a2 = fdot2(h2(w2.x), hh0, a2); a2 = fdot2(h2(w2.y), hh1, a2);
            a2 = fdot2(h2(w2.z), hh2, a2); a2 = fdot2(h2(w2.w), hh3, a2);
            a3 = fdot2(h2(w3.x), hh0, a3); a3 = fdot2(h2(w3.y), hh1, a3);
            a3 = fdot2(h2(w3.z), hh2, a3); a3 = fdot2(h2(w3.w), hh3, a3);
        }
        float iv = sigm(a0 + gi);
        float fv = sigm(a1 + gf);
        float gv = tanh_fast(a2 + gg);
        float ov = sigm(a3 + go);
        c = fv * c + iv * gv;
        float h = ov * tanh_fast(c);
        __syncthreads();               // all reads of hsh done
        hsh[j] = (_Float16)h;
        hob[t * 256 + j] = h;          // coalesced fp32 write
        __syncthreads();               // h visible before next step
    }
}

// ---------------------------------------------------------------------------
// fc_softmax: logits = h[b,511,:] @ fc_w^T + fc_b, softmax over 3 classes
// ---------------------------------------------------------------------------
__global__ __launch_bounds__(64) void fc_softmax(const float* __restrict__ h1,
                                                 const float* __restrict__ fcw,
                                                 const float* __restrict__ fcb,
                                                 float* __restrict__ out) {
    const int b = blockIdx.x;
    const int lane = threadIdx.x;  // 0..63
    const float* h = h1 + ((size_t)b * 512 + 511) * 256;
    float p0 = 0.f, p1 = 0.f, p2 = 0.f;
    for (int k = lane; k < 256; k += 64) {
        float hv = h[k];
        p0 += hv * fcw[k];
        p1 += hv * fcw[256 + k];
        p2 += hv * fcw[512 + k];
    }
#pragma unroll
    for (int off = 32; off > 0; off >>= 1) {
        p0 += __shfl_down(p0, off);
        p1 += __shfl_down(p1, off);
        p2 += __shfl_down(p2, off);
    }
    if (lane == 0) {
        float l0 = p0 + fcb[0], l1 = p1 + fcb[1], l2 = p2 + fcb[2];
        float m = fmaxf(l0, fmaxf(l1, l2));
        float e0 = __expf(l0 - m), e1 = __expf(l1 - m), e2 = __expf(l2 - m);
        float s = 1.f / (e0 + e1 + e2);
        out[b * 3 + 0] = e0 * s;
        out[b * 3 + 1] = e1 * s;
        out[b * 3 + 2] = e2 * s;
    }
}

extern "C" void kernel_launch(void* const* d_in, const int* in_sizes, int n_in,
                              void* d_out, int out_size, void* d_ws, size_t ws_size,
                              hipStream_t stream) {
    const float* x    = (const float*)d_in[0];
    const float* Wih0 = (const float*)d_in[1];
    const float* Whh0 = (const float*)d_in[2];
    const float* bih0 = (const float*)d_in[3];
    const float* bhh0 = (const float*)d_in[4];
    const float* Wih1 = (const float*)d_in[5];
    const float* Whh1 = (const float*)d_in[6];
    const float* bih1 = (const float*)d_in[7];
    const float* bhh1 = (const float*)d_in[8];
    const float* fcw  = (const float*)d_in[9];
    const float* fcb  = (const float*)d_in[10];
    float* out = (float*)d_out;

    // workspace layout (~161 MB total)
    char* ws = (char*)d_ws;
    float* gx = (float*)ws;        ws += (size_t)64 * 512 * 1024 * 4;  // 134 MB
    float* h0 = (float*)ws;        ws += (size_t)64 * 512 * 256 * 4;   // 33.5 MB
    uint4* Wp0 = (uint4*)ws;       ws += (size_t)1024 * 256 * 2;       // 512 KB
    uint4* Wp1 = (uint4*)ws;       ws += (size_t)1024 * 256 * 2;       // 512 KB
    float* bias0 = (float*)ws;     ws += 4096;
    float* bias1 = (float*)ws;     ws += 4096;

    prep_whh<<<128, 256, 0, stream>>>(Whh0, bih0, bhh0, Wp0, bias0);
    prep_whh<<<128, 256, 0, stream>>>(Whh1, bih1, bhh1, Wp1, bias1);

    // layer 0: gates_x = x @ W_ih_0^T + bias0   (M=32768, K=128)
    gemm_bias<<<dim3(512, 16), 256, 0, stream>>>(x, Wih0, bias0, gx, 128);
    lstm_scan<<<64, 256, 0, stream>>>(gx, Wp0, h0);

    // layer 1: gates_x = h0 @ W_ih_1^T + bias1  (M=32768, K=256)
    gemm_bias<<<dim3(512, 16), 256, 0, stream>>>(h0, Wih1, bias1, gx, 256);
    lstm_scan<<<64, 256, 0, stream>>>(gx, Wp1, h0);  // h1 overwrites h0 (safe: h0 consumed)

    fc_softmax<<<64, 64, 0, stream>>>(h0, fcw, fcb, out);
}

// Round 2
// 3220.648 us; speedup vs baseline: 1.9967x; 1.9967x over previous
//
#include <hip/hip_runtime.h>
#include <cstdint>
#include <cstddef>

// Problem: B=64, T=512, I=128, H=256, 4H=1024, C=3. All fp32 in/out.
typedef _Float16 half2_t __attribute__((ext_vector_type(2)));
typedef _Float16 half8_t __attribute__((ext_vector_type(8)));
typedef float f32x4 __attribute__((ext_vector_type(4)));

static __device__ __forceinline__ float fdot2(half2_t a, half2_t b, float c) {
    return __builtin_amdgcn_fdot2(a, b, c, false);
}
static __device__ __forceinline__ half2_t h2(unsigned int u) {
    return __builtin_bit_cast(half2_t, u);
}
static __device__ __forceinline__ float sigm(float x) {
    return 1.f / (1.f + __expf(-x));
}
static __device__ __forceinline__ float tanh_fast(float x) {
    float ax = fabsf(x);
    float e = __expf(2.f * ax);
    float r = 1.f - 2.f / (e + 1.f);
    return copysignf(r, x);
}

// ---------------------------------------------------------------------------
// prep: W_hh (1024x256 fp32) -> f16 k8-major: Wp[k8*1024 + row] = 8 halves of
// W[row][8*k8..]; bias = b_ih + b_hh
// ---------------------------------------------------------------------------
__global__ __launch_bounds__(256) void prep_whh(const float* __restrict__ Whh,
                                                const float* __restrict__ bih,
                                                const float* __restrict__ bhh,
                                                uint4* __restrict__ Wp,
                                                float* __restrict__ bias) {
    int n = blockIdx.x * 256 + threadIdx.x;  // 0..32767
    if (n < 1024) bias[n] = bih[n] + bhh[n];
    int row = n & 1023;
    int k8 = n >> 10;
    union { uint4 u; _Float16 h[8]; } cv;
#pragma unroll
    for (int j = 0; j < 8; ++j) cv.h[j] = (_Float16)Whh[row * 256 + k8 * 8 + j];
    Wp[k8 * 1024 + row] = cv.u;
}

// f32 -> f16, 4 elements/thread (n must be /4)
__global__ __launch_bounds__(256) void cvt_f16(const float* __restrict__ in,
                                               _Float16* __restrict__ out, int n4) {
    int i = blockIdx.x * 256 + threadIdx.x;
    if (i < n4) {
        float4 v = ((const float4*)in)[i];
        union { ushort4 u; _Float16 h[4]; } cv;
        cv.h[0] = (_Float16)v.x; cv.h[1] = (_Float16)v.y;
        cv.h[2] = (_Float16)v.z; cv.h[3] = (_Float16)v.w;
        ((ushort4*)out)[i] = cv.u;
    }
}

// ---------------------------------------------------------------------------
// gemm_mfma: C[M][1024] = A[M][K](f16) * W[1024][K](f16)^T + bias, fp32 out.
// 64x64 tile / WG (256 thr = 4 waves); wave w does rows [w*16, w*16+16).
// mfma_f32_16x16x32_f16. A/B frag: [r=lane&15][k=quad*8+j]; D: row=quad*4+i,
// col=lane&15 (HW-verified layouts).
// ---------------------------------------------------------------------------
__global__ __launch_bounds__(256) void gemm_mfma(const _Float16* __restrict__ A,
                                                 const _Float16* __restrict__ Bw,
                                                 const float* __restrict__ bias,
                                                 float* __restrict__ Cmat, int K) {
    __shared__ _Float16 As[64][72];  // +8 pad: 2-way max bank aliasing (free)
    __shared__ _Float16 Bs[64][72];
    const int tid = threadIdx.x;
    const int wave = tid >> 6, lane = tid & 63;
    const int quad = lane >> 4, l16 = lane & 15;
    const int m0 = blockIdx.x * 64, n0 = blockIdx.y * 64;
    const int sr = tid >> 2;        // staging row 0..63
    const int sc = (tid & 3) * 16;  // staging col (f16) 0,16,32,48

    f32x4 acc[4] = {};  // 4 n-blocks of 16

    for (int k0 = 0; k0 < K; k0 += 64) {
        const uint4 a0v = *(const uint4*)(A + (size_t)(m0 + sr) * K + k0 + sc);
        const uint4 a1v = *(const uint4*)(A + (size_t)(m0 + sr) * K + k0 + sc + 8);
        const uint4 b0v = *(const uint4*)(Bw + (size_t)(n0 + sr) * K + k0 + sc);
        const uint4 b1v = *(const uint4*)(Bw + (size_t)(n0 + sr) * K + k0 + sc + 8);
        __syncthreads();  // prev-iter frag reads done before overwrite
        *(uint4*)&As[sr][sc] = a0v;
        *(uint4*)&As[sr][sc + 8] = a1v;
        *(uint4*)&Bs[sr][sc] = b0v;
        *(uint4*)&Bs[sr][sc + 8] = b1v;
        __syncthreads();
#pragma unroll
        for (int kc = 0; kc < 64; kc += 32) {
            half8_t af = *(const half8_t*)&As[wave * 16 + l16][kc + quad * 8];
#pragma unroll
            for (int nb = 0; nb < 4; ++nb) {
                half8_t bf = *(const half8_t*)&Bs[nb * 16 + l16][kc + quad * 8];
                acc[nb] = __builtin_amdgcn_mfma_f32_16x16x32_f16(af, bf, acc[nb], 0, 0, 0);
            }
        }
    }
#pragma unroll
    for (int nb = 0; nb < 4; ++nb) {
#pragma unroll
        for (int i = 0; i < 4; ++i) {
            int row = m0 + wave * 16 + quad * 4 + i;
            int col = n0 + nb * 16 + l16;
            Cmat[(size_t)row * 1024 + col] = acc[nb][i] + bias[col];
        }
    }
}

// ---------------------------------------------------------------------------
// lstm_scan v2: 64 WGs x 256 thr. Thread j owns unit j (gate rows j, 256+j,
// 512+j, 768+j). k<128 of all 4 rows held in 256 VGPRs (persistent across
// all 512 steps); k in [128,256) streamed from L2 with 2-deep pipeline.
// h double-buffered in LDS (f16) -> ONE barrier/step. h_out written f16.
// ---------------------------------------------------------------------------
__global__ __launch_bounds__(256, 1) void lstm_scan(const float* __restrict__ gx,
                                                    const uint4* __restrict__ Wp,
                                                    _Float16* __restrict__ h_out) {
    const int b = blockIdx.x;
    const int j = threadIdx.x;
    __shared__ _Float16 hsh[2][256] __attribute__((aligned(16)));

    // persistent register weights: k8 = 0..15 (k < 128), 4 rows
    uint4 w0[16], w1[16], w2[16], w3[16];
#pragma unroll
    for (int u = 0; u < 16; ++u) {
        w0[u] = Wp[u * 1024 + j];
        w1[u] = Wp[u * 1024 + 256 + j];
        w2[u] = Wp[u * 1024 + 512 + j];
        w3[u] = Wp[u * 1024 + 768 + j];
    }
    const uint4* WpHi = Wp + 16 * 1024;  // k8 = 16..31

    hsh[0][j] = (_Float16)0.f;
    float c = 0.f;
    const float* gxb = gx + (size_t)b * 512 * 1024;
    _Float16* hob = h_out + (size_t)b * 512 * 256;
    __syncthreads();

    for (int t = 0; t < 512; ++t) {
        const float* g4 = gxb + t * 1024;
        // gx loads (HBM/L3): issue first, consumed at the end
        float gi = g4[j], gf = g4[256 + j], gg = g4[512 + j], go = g4[768 + j];

        const uint4* hb = (const uint4*)hsh[t & 1];
        float a0 = 0.f, a1 = 0.f, a2 = 0.f, a3 = 0.f;

        // streamed-weight pipeline: prefetch chunks 0,1 (k8=16,17)
        uint4 pa = WpHi[j],        pb = WpHi[256 + j],        pc = WpHi[512 + j],        pd = WpHi[768 + j];
        uint4 qa = WpHi[1024 + j], qb = WpHi[1024 + 256 + j], qc = WpHi[1024 + 512 + j], qd = WpHi[1024 + 768 + j];

        // register half: k8 = 0..15 (covers stream latency)
#pragma unroll
        for (int u = 0; u < 16; ++u) {
            const uint4 hv = hb[u];
            const half2_t h0 = h2(hv.x), h1 = h2(hv.y), h22 = h2(hv.z), h3 = h2(hv.w);
            a0 = fdot2(h2(w0[u].x), h0, a0); a0 = fdot2(h2(w0[u].y), h1, a0);
            a0 = fdot2(h2(w0[u].z), h22, a0); a0 = fdot2(h2(w0[u].w), h3, a0);
            a1 = fdot2(h2(w1[u].x), h0, a1); a1 = fdot2(h2(w1[u].y), h1, a1);
            a1 = fdot2(h2(w1[u].z), h22, a1); a1 = fdot2(h2(w1[u].w), h3, a1);
            a2 = fdot2(h2(w2[u].x), h0, a2); a2 = fdot2(h2(w2[u].y), h1, a2);
            a2 = fdot2(h2(w2[u].z), h22, a2); a2 = fdot2(h2(w2[u].w), h3, a2);
            a3 = fdot2(h2(w3[u].x), h0, a3); a3 = fdot2(h2(w3[u].y), h1, a3);
            a3 = fdot2(h2(w3[u].z), h22, a3); a3 = fdot2(h2(w3[u].w), h3, a3);
        }
        // streamed half: k8 = 16..31, rolling 2-ahead prefetch
#pragma unroll
        for (int u = 0; u < 16; ++u) {
            const uint4 ca = pa, cb = pb, cc = pc, cd = pd;
            pa = qa; pb = qb; pc = qc; pd = qd;
            if (u < 14) {
                qa = WpHi[(u + 2) * 1024 + j];
                qb = WpHi[(u + 2) * 1024 + 256 + j];
                qc = WpHi[(u + 2) * 1024 + 512 + j];
                qd = WpHi[(u + 2) * 1024 + 768 + j];
            }
            const uint4 hv = hb[16 + u];
            const half2_t h0 = h2(hv.x), h1 = h2(hv.y), h22 = h2(hv.z), h3 = h2(hv.w);
            a0 = fdot2(h2(ca.x), h0, a0); a0 = fdot2(h2(ca.y), h1, a0);
            a0 = fdot2(h2(ca.z), h22, a0); a0 = fdot2(h2(ca.w), h3, a0);
            a1 = fdot2(h2(cb.x), h0, a1); a1 = fdot2(h2(cb.y), h1, a1);
            a1 = fdot2(h2(cb.z), h22, a1); a1 = fdot2(h2(cb.w), h3, a1);
            a2 = fdot2(h2(cc.x), h0, a2); a2 = fdot2(h2(cc.y), h1, a2);
            a2 = fdot2(h2(cc.z), h22, a2); a2 = fdot2(h2(cc.w), h3, a2);
            a3 = fdot2(h2(cd.x), h0, a3); a3 = fdot2(h2(cd.y), h1, a3);
            a3 = fdot2(h2(cd.z), h22, a3); a3 = fdot2(h2(cd.w), h3, a3);
        }

        float iv = sigm(a0 + gi);
        float fv = sigm(a1 + gf);
        float gv = tanh_fast(a2 + gg);
        float ov = sigm(a3 + go);
        c = fv * c + iv * gv;
        float h = ov * tanh_fast(c);

        _Float16 hh = (_Float16)h;
        hsh[(t + 1) & 1][j] = hh;   // write OTHER buffer: no WAR with this step's reads
        hob[t * 256 + j] = hh;      // f16 coalesced store
        __syncthreads();            // one barrier/step
    }
}

// ---------------------------------------------------------------------------
// fc_softmax: logits = h[b,511,:](f16) @ fc_w^T + fc_b, softmax over 3
// ---------------------------------------------------------------------------
__global__ __launch_bounds__(64) void fc_softmax(const _Float16* __restrict__ h1,
                                                 const float* __restrict__ fcw,
                                                 const float* __restrict__ fcb,
                                                 float* __restrict__ out) {
    const int b = blockIdx.x;
    const int lane = threadIdx.x;
    const _Float16* h = h1 + ((size_t)b * 512 + 511) * 256;
    float p0 = 0.f, p1 = 0.f, p2 = 0.f;
    for (int k = lane; k < 256; k += 64) {
        float hv = (float)h[k];
        p0 += hv * fcw[k];
        p1 += hv * fcw[256 + k];
        p2 += hv * fcw[512 + k];
    }
#pragma unroll
    for (int off = 32; off > 0; off >>= 1) {
        p0 += __shfl_down(p0, off);
        p1 += __shfl_down(p1, off);
        p2 += __shfl_down(p2, off);
    }
    if (lane == 0) {
        float l0 = p0 + fcb[0], l1 = p1 + fcb[1], l2 = p2 + fcb[2];
        float m = fmaxf(l0, fmaxf(l1, l2));
        float e0 = __expf(l0 - m), e1 = __expf(l1 - m), e2 = __expf(l2 - m);
        float s = 1.f / (e0 + e1 + e2);
        out[b * 3 + 0] = e0 * s;
        out[b * 3 + 1] = e1 * s;
        out[b * 3 + 2] = e2 * s;
    }
}

extern "C" void kernel_launch(void* const* d_in, const int* in_sizes, int n_in,
                              void* d_out, int out_size, void* d_ws, size_t ws_size,
                              hipStream_t stream) {
    const float* x    = (const float*)d_in[0];
    const float* Wih0 = (const float*)d_in[1];
    const float* Whh0 = (const float*)d_in[2];
    const float* bih0 = (const float*)d_in[3];
    const float* bhh0 = (const float*)d_in[4];
    const float* Wih1 = (const float*)d_in[5];
    const float* Whh1 = (const float*)d_in[6];
    const float* bih1 = (const float*)d_in[7];
    const float* bhh1 = (const float*)d_in[8];
    const float* fcw  = (const float*)d_in[9];
    const float* fcb  = (const float*)d_in[10];
    float* out = (float*)d_out;

    // workspace layout (~161 MB)
    char* ws = (char*)d_ws;
    float* gx        = (float*)ws;     ws += (size_t)32768 * 1024 * 4;  // 134.2 MB
    _Float16* h0f    = (_Float16*)ws;  ws += (size_t)32768 * 256 * 2;   // 16.8 MB
    _Float16* xh     = (_Float16*)ws;  ws += (size_t)32768 * 128 * 2;   // 8.4 MB
    _Float16* Wih0h  = (_Float16*)ws;  ws += (size_t)1024 * 128 * 2;    // 256 KB
    _Float16* Wih1h  = (_Float16*)ws;  ws += (size_t)1024 * 256 * 2;    // 512 KB
    uint4* Wp0       = (uint4*)ws;     ws += (size_t)1024 * 256 * 2;    // 512 KB
    uint4* Wp1       = (uint4*)ws;     ws += (size_t)1024 * 256 * 2;    // 512 KB
    float* bias0     = (float*)ws;     ws += 4096;
    float* bias1     = (float*)ws;     ws += 4096;

    prep_whh<<<128, 256, 0, stream>>>(Whh0, bih0, bhh0, Wp0, bias0);
    prep_whh<<<128, 256, 0, stream>>>(Whh1, bih1, bhh1, Wp1, bias1);
    cvt_f16<<<4096, 256, 0, stream>>>(x, xh, 32768 * 128 / 4);
    cvt_f16<<<128, 256, 0, stream>>>(Wih0, Wih0h, 1024 * 128 / 4);
    cvt_f16<<<256, 256, 0, stream>>>(Wih1, Wih1h, 1024 * 256 / 4);

    // layer 0
    gemm_mfma<<<dim3(512, 16), 256, 0, stream>>>(xh, Wih0h, bias0, gx, 128);
    lstm_scan<<<64, 256, 0, stream>>>(gx, Wp0, h0f);

    // layer 1
    gemm_mfma<<<dim3(512, 16), 256, 0, stream>>>(h0f, Wih1h, bias1, gx, 256);
    lstm_scan<<<64, 256, 0, stream>>>(gx, Wp1, h0f);  // overwrite: h0f consumed

    fc_softmax<<<64, 64, 0, stream>>>(h0f, fcw, fcb, out);
}